// Round 10
// baseline (1000.280 us; speedup 1.0000x reference)
//
#include <hip/hip_runtime.h>

typedef unsigned short ushort_t;
typedef _Float16 f16x8 __attribute__((ext_vector_type(8)));
typedef float f32x4 __attribute__((ext_vector_type(4)));
typedef float f32x2 __attribute__((ext_vector_type(2)));

#define H_DIM 256
#define OUT_DIM 256

__device__ inline float lrelu(float v) { return v > 0.f ? v : 0.01f * v; }

__device__ inline unsigned short f2h(float f) {
    _Float16 h = (_Float16)f;
    unsigned short u;
    __builtin_memcpy(&u, &h, 2);
    return u;
}

__device__ inline float h2f(unsigned short u) {
    _Float16 h;
    __builtin_memcpy(&h, &u, 2);
    return (float)h;
}

// ---------- prep kernels ----------

__global__ void k_gather_x0(const float* __restrict__ sst, const int* __restrict__ mask,
                            float* __restrict__ x0, int NT, int Nn, int F) {
    int v = blockIdx.x * 256 + threadIdx.x;
    if (v < NT) {
        int b = v / Nn;
        int i = v - b * Nn;
        x0[v] = sst[(size_t)b * F + mask[i]];
    }
}

__global__ void k_count(const int* __restrict__ dst, int* __restrict__ cnt, int E) {
    int e = blockIdx.x * 256 + threadIdx.x;
    if (e < E) atomicAdd(&cnt[dst[e]], 1);
}

__global__ void k_dis(const int* __restrict__ cnt, float* __restrict__ dis, int NT) {
    int v = blockIdx.x * 256 + threadIdx.x;
    if (v < NT) dis[v] = rsqrtf((float)cnt[v] + 1.0f);
}

__global__ void k_scan_block(const int* __restrict__ cnt, int* __restrict__ bsum, int NT) {
    __shared__ int s[256];
    int i = blockIdx.x * 256 + threadIdx.x;
    s[threadIdx.x] = (i < NT) ? cnt[i] : 0;
    __syncthreads();
    for (int o = 128; o > 0; o >>= 1) {
        if (threadIdx.x < o) s[threadIdx.x] += s[threadIdx.x + o];
        __syncthreads();
    }
    if (threadIdx.x == 0) bsum[blockIdx.x] = s[0];
}

__global__ void k_scan_top(const int* __restrict__ bsum, int* __restrict__ bpre, int nb) {
    __shared__ int s[512];
    int t = threadIdx.x;
    int v = (t < nb) ? bsum[t] : 0;
    s[t] = v;
    __syncthreads();
    for (int o = 1; o < nb; o <<= 1) {
        int add = (t >= o) ? s[t - o] : 0;
        __syncthreads();
        s[t] += add;
        __syncthreads();
    }
    if (t < nb) bpre[t] = s[t] - v;   // exclusive
}

__global__ void k_scan_scatter(const int* __restrict__ cnt, const int* __restrict__ bpre,
                               int* __restrict__ startp, int* __restrict__ cursor, int NT) {
    __shared__ int s[256];
    int t = threadIdx.x;
    int i = blockIdx.x * 256 + t;
    int v = (i < NT) ? cnt[i] : 0;
    s[t] = v;
    __syncthreads();
    for (int o = 1; o < 256; o <<= 1) {
        int add = (t >= o) ? s[t - o] : 0;
        __syncthreads();
        s[t] += add;
        __syncthreads();
    }
    int excl = s[t] - v + bpre[blockIdx.x];
    if (i < NT) { startp[i] = excl; cursor[i] = excl; }
}

// fill: single 4B scatter per edge (weights derived from dis table at use time)
__global__ void k_fill(const int* __restrict__ src, const int* __restrict__ dst,
                       int* __restrict__ cursor, int* __restrict__ csrc, int E) {
    int e = blockIdx.x * 256 + threadIdx.x;
    if (e < E) {
        int s = src[e], d = dst[e];
        int p = atomicAdd(&cursor[d], 1);
        csrc[p] = s;
    }
}

__global__ void k_prepW(const float* __restrict__ Ws, ushort_t* __restrict__ Wt, int total) {
    int idx = blockIdx.x * 256 + threadIdx.x;
    if (idx < total) {
        int l = idx >> 16;          // layer
        int rem = idx & 65535;
        int k = rem >> 8;           // input dim
        int n = rem & 255;          // output dim
        Wt[(l << 16) + (n << 8) + k] = f2h(Ws[idx]);
    }
}

// ---------- layer 1 (scalar input) ----------

__global__ void k_agg0(const float* __restrict__ x0, const int* __restrict__ startp,
                       const int* __restrict__ cnt, const int* __restrict__ csrc,
                       const float* __restrict__ dis, float* __restrict__ y0, int NT) {
    int v = blockIdx.x * 256 + threadIdx.x;
    if (v >= NT) return;
    float dd = dis[v];
    float acc = dd * x0[v];                 // self: dd^2 x0 after final *dd
    int s = startp[v], e = s + cnt[v];
    for (int i = s; i < e; i++) {
        int sv = csrc[i];
        acc += dis[sv] * x0[sv];
    }
    y0[v] = dd * acc;
}

__global__ void k_expand(const float* __restrict__ x0, const float* __restrict__ y0,
                         const float* __restrict__ W1, const float* __restrict__ b1,
                         ushort_t* __restrict__ xh, int NT) {
    int idx = blockIdx.x * 256 + threadIdx.x;      // one float4-worth each, NT*64 total
    int v = idx >> 6;
    int q = idx & 63;
    if (v >= NT) return;
    float xv = x0[v], yv = y0[v];
    float4 w = ((const float4*)W1)[q];
    float4 b = ((const float4*)b1)[q];
    ushort4 o;
    o.x = f2h(xv + lrelu(yv * w.x + b.x));
    o.y = f2h(xv + lrelu(yv * w.y + b.y));
    o.z = f2h(xv + lrelu(yv * w.z + b.z));
    o.w = f2h(xv + lrelu(yv * w.w + b.w));
    ((ushort4*)xh)[(size_t)v * 64 + q] = o;
}

// ---------- GEMM: z = xh @ W (fp16 MFMA, f32 acc, fp8 e4m3 out) ----------
// W held in REGISTERS (loaded once/block from L2); A staged once per 64-row tile
// for the FULL K=256 with XOR-swizzled LDS ([row][col^((row&7)<<4)]).
// Block: 256 thr = 4 waves, wave w owns cols [w*64, w*64+64) of all 64 rows.
// Grid-stride over NT/64 tiles. One barrier pair per tile.

__global__ __launch_bounds__(256) void k_gemm(const ushort_t* __restrict__ xh,
                                              const ushort_t* __restrict__ Wt,
                                              unsigned char* __restrict__ z, int NT) {
    __shared__ __align__(16) char AsRaw[64 * 512];    // 32 KB: 64 rows x 512B (swizzled)
    __shared__ __align__(16) char Rep[4][4096];       // 16 KB: per-wave fp8 repack
    int tid = threadIdx.x;
    int wave = tid >> 6, lane = tid & 63;
    int rl = lane & 15, hi = lane >> 4;               // hi in 0..3

    // ---- W fragments into registers: wave owns n-cols [wave*64, +64) ----
    f16x8 bf[4][8];
    #pragma unroll
    for (int ni = 0; ni < 4; ni++)
        #pragma unroll
        for (int c = 0; c < 8; c++)
            bf[ni][c] = *(const f16x8*)(Wt + (size_t)(wave * 64 + ni * 16 + rl) * 256
                                        + c * 32 + hi * 8);

    int ntiles = NT / 64;
    for (int t = blockIdx.x; t < ntiles; t += gridDim.x) {
        size_t rowbase = (size_t)t * 64;

        // ---- stage A tile: 64 rows x 256 fp16, swizzled write ----
        #pragma unroll
        for (int p = 0; p < 8; p++) {
            int idx = p * 256 + tid;          // 2048 chunks of 16B
            int row = idx >> 5;
            int colb = (idx & 31) * 16;
            uint4 vsrc = *(const uint4*)(xh + (rowbase + row) * H_DIM + (idx & 31) * 8);
            *(uint4*)(AsRaw + row * 512 + (colb ^ ((row & 7) << 4))) = vsrc;
        }
        __syncthreads();

        // ---- MFMA: 8 k-chunks x (4 mi x 4 ni) ----
        f32x4 acc[4][4];
        #pragma unroll
        for (int mi = 0; mi < 4; mi++)
            #pragma unroll
            for (int ni = 0; ni < 4; ni++)
                acc[mi][ni] = (f32x4){0.f, 0.f, 0.f, 0.f};

        #pragma unroll
        for (int c = 0; c < 8; c++) {
            f16x8 af[4];
            #pragma unroll
            for (int mi = 0; mi < 4; mi++) {
                int row = mi * 16 + rl;
                int colb = c * 64 + hi * 16;
                af[mi] = *(const f16x8*)(AsRaw + row * 512 + (colb ^ ((row & 7) << 4)));
            }
            #pragma unroll
            for (int mi = 0; mi < 4; mi++)
                #pragma unroll
                for (int ni = 0; ni < 4; ni++)
                    acc[mi][ni] = __builtin_amdgcn_mfma_f32_16x16x32_f16(
                        af[mi], bf[ni][c], acc[mi][ni], 0, 0, 0);
        }
        __syncthreads();   // As free for next tile's stage

        // ---- epilogue: fp8 pack -> per-wave LDS slice -> coalesced stores ----
        char* slice = &Rep[wave][0];
        #pragma unroll
        for (int mi = 0; mi < 4; mi++)
            #pragma unroll
            for (int ni = 0; ni < 4; ni++)
                #pragma unroll
                for (int r = 0; r < 4; r++) {
                    float vv = acc[mi][ni][r];
                    int pk = __builtin_amdgcn_cvt_pk_fp8_f32(vv, vv, 0, false);
                    slice[(mi * 16 + hi * 4 + r) * 64 + ni * 16 + rl] = (char)(pk & 0xFF);
                }
        #pragma unroll
        for (int p = 0; p < 4; p++) {
            uint4 val = *(const uint4*)(slice + p * 1024 + lane * 16);
            int lrow = p * 16 + (lane >> 2);
            int lcolb = (lane & 3) * 16;
            *(uint4*)(z + (rowbase + lrow) * 256 + wave * 64 + lcolb) = val;
        }
    }
}

// ---------- aggregate + bias + leaky + residual (in-place fp16 xh update) ----------
// One 64-lane wave per node; fp8 z rows (256B, 1 dword/lane), unroll-4 gather.
// Edge weight = dis[src]*dis[dst], with dis[dst] hoisted out of the sum.

__global__ void k_aggres(const unsigned char* __restrict__ z, const int* __restrict__ startp,
                         const int* __restrict__ cnt, const int* __restrict__ csrc,
                         const float* __restrict__ dis, const float* __restrict__ bias,
                         ushort_t* __restrict__ xh, int NT) {
    int gid = blockIdx.x * blockDim.x + threadIdx.x;
    int v = gid >> 6;
    int lane = threadIdx.x & 63;
    if (v >= NT) return;

    // hoisted independent loads (in flight during gather)
    float dd = dis[v];
    int s = startp[v], e = s + cnt[v];
    unsigned int a = *(const unsigned int*)(z + (size_t)v * 256 + lane * 4);
    ushort4 xr = *(const ushort4*)(xh + (size_t)v * H_DIM + lane * 4);
    float4 bv = *(const float4*)(bias + lane * 4);

    // inner = dd*z[v] + sum dis[s]*z[s]; final acc = dd*inner
    f32x2 a01 = __builtin_amdgcn_cvt_pk_f32_fp8(a, false);
    f32x2 a23 = __builtin_amdgcn_cvt_pk_f32_fp8(a, true);
    float acc0 = dd * a01[0], acc1 = dd * a01[1];
    float acc2 = dd * a23[0], acc3 = dd * a23[1];

    int i = s;
    for (; i + 4 <= e; i += 4) {
        int i0 = csrc[i], i1 = csrc[i + 1], i2 = csrc[i + 2], i3 = csrc[i + 3];
        float w0 = dis[i0], w1 = dis[i1], w2 = dis[i2], w3 = dis[i3];
        unsigned int b0 = *(const unsigned int*)(z + (size_t)i0 * 256 + lane * 4);
        unsigned int b1 = *(const unsigned int*)(z + (size_t)i1 * 256 + lane * 4);
        unsigned int b2 = *(const unsigned int*)(z + (size_t)i2 * 256 + lane * 4);
        unsigned int b3 = *(const unsigned int*)(z + (size_t)i3 * 256 + lane * 4);
        f32x2 p0 = __builtin_amdgcn_cvt_pk_f32_fp8(b0, false);
        f32x2 q0 = __builtin_amdgcn_cvt_pk_f32_fp8(b0, true);
        f32x2 p1 = __builtin_amdgcn_cvt_pk_f32_fp8(b1, false);
        f32x2 q1 = __builtin_amdgcn_cvt_pk_f32_fp8(b1, true);
        f32x2 p2 = __builtin_amdgcn_cvt_pk_f32_fp8(b2, false);
        f32x2 q2 = __builtin_amdgcn_cvt_pk_f32_fp8(b2, true);
        f32x2 p3 = __builtin_amdgcn_cvt_pk_f32_fp8(b3, false);
        f32x2 q3 = __builtin_amdgcn_cvt_pk_f32_fp8(b3, true);
        acc0 += w0 * p0[0] + w1 * p1[0] + w2 * p2[0] + w3 * p3[0];
        acc1 += w0 * p0[1] + w1 * p1[1] + w2 * p2[1] + w3 * p3[1];
        acc2 += w0 * q0[0] + w1 * q1[0] + w2 * q2[0] + w3 * q3[0];
        acc3 += w0 * q0[1] + w1 * q1[1] + w2 * q2[1] + w3 * q3[1];
    }
    for (; i < e; i++) {
        int sv = csrc[i];
        float nw = dis[sv];
        unsigned int b = *(const unsigned int*)(z + (size_t)sv * 256 + lane * 4);
        f32x2 p = __builtin_amdgcn_cvt_pk_f32_fp8(b, false);
        f32x2 q = __builtin_amdgcn_cvt_pk_f32_fp8(b, true);
        acc0 += nw * p[0]; acc1 += nw * p[1];
        acc2 += nw * q[0]; acc3 += nw * q[1];
    }

    ushort4 o;
    o.x = f2h(h2f(xr.x) + lrelu(dd * acc0 + bv.x));
    o.y = f2h(h2f(xr.y) + lrelu(dd * acc1 + bv.y));
    o.z = f2h(h2f(xr.z) + lrelu(dd * acc2 + bv.z));
    o.w = f2h(h2f(xr.w) + lrelu(dd * acc3 + bv.w));
    *(ushort4*)(xh + (size_t)v * H_DIM + lane * 4) = o;
}

// ---------- pooling (3-stage tree) + head ----------

__global__ void k_pool1(const ushort_t* __restrict__ xh, float* __restrict__ partial) {
    __shared__ float s[4][256];
    int t = threadIdx.x;
    int w = t >> 6, lane = t & 63;
    size_t nodebase = (size_t)blockIdx.x * 64;
    float4 acc = make_float4(0.f, 0.f, 0.f, 0.f);
    for (int i = 0; i < 16; i++) {
        size_t node = nodebase + i * 4 + w;
        ushort4 v = *(const ushort4*)(xh + node * H_DIM + lane * 4);
        acc.x += h2f(v.x); acc.y += h2f(v.y); acc.z += h2f(v.z); acc.w += h2f(v.w);
    }
    *(float4*)&s[w][lane * 4] = acc;
    __syncthreads();
    float sum = s[0][t] + s[1][t] + s[2][t] + s[3][t];
    partial[(size_t)blockIdx.x * H_DIM + t] = sum;
}

__global__ void k_pool2(const float* __restrict__ partial, float* __restrict__ partial2,
                        int rowsPerChunk) {
    int blk = blockIdx.x, t = threadIdx.x;
    size_t rowbase = (size_t)blk * rowsPerChunk;
    float s = 0.f;
    for (int j = 0; j < rowsPerChunk; j++)
        s += partial[(rowbase + j) * H_DIM + t];
    partial2[(size_t)blk * H_DIM + t] = s;
}

__global__ void k_pool3(const float* __restrict__ partial2, float* __restrict__ pooled,
                        int chunksPerBatch, float inv) {
    int b = blockIdx.x, t = threadIdx.x;
    float s = 0.f;
    for (int j = 0; j < chunksPerBatch; j++)
        s += partial2[((size_t)b * chunksPerBatch + j) * H_DIM + t];
    pooled[b * H_DIM + t] = s * inv;
}

__global__ void k_head(const float* __restrict__ pooled, const float* __restrict__ Wh,
                       const float* __restrict__ bh, float* __restrict__ out) {
    int b = blockIdx.x, o = threadIdx.x;
    float acc = bh[o];
    for (int h = 0; h < H_DIM; h++) acc += pooled[b * H_DIM + h] * Wh[h * OUT_DIM + o];
    out[b * OUT_DIM + o] = acc;
}

// ---------- host ----------

extern "C" void kernel_launch(void* const* d_in, const int* in_sizes, int n_in,
                              void* d_out, int out_size, void* d_ws, size_t ws_size,
                              hipStream_t stream) {
    const float* sst  = (const float*)d_in[0];
    const int*   mask = (const int*)d_in[1];
    const int*   eidx = (const int*)d_in[2];
    const float* W1   = (const float*)d_in[3];
    const float* b1   = (const float*)d_in[4];
    const float* Ws   = (const float*)d_in[5];
    const float* bs   = (const float*)d_in[6];
    const float* Wh   = (const float*)d_in[7];
    const float* bh   = (const float*)d_in[8];

    const int B  = out_size / OUT_DIM;               // 2
    const int Nn = in_sizes[1];                      // 65536
    const int E  = in_sizes[2] / 2;                  // 1048576
    const int F  = in_sizes[0] / B;                  // 686364
    const int DEPTH = in_sizes[5] / (H_DIM * H_DIM); // 8
    const int NT = B * Nn;                           // 131072

    // workspace carve-up (256B aligned) — total ~140 MB
    size_t off = 0;
    char* base = (char*)d_ws;
    auto alloc = [&](size_t bytes) -> void* {
        void* p = base + off;
        off += (bytes + 255) & ~(size_t)255;
        return p;
    };
    ushort_t*      xh      = (ushort_t*)alloc((size_t)NT * H_DIM * 2);  // 67.1 MB fp16 residual
    unsigned char* zbuf    = (unsigned char*)alloc((size_t)NT * 256);   // 33.5 MB fp8
    float*    x0      = (float*)alloc((size_t)NT * 4);
    float*    y0      = (float*)alloc((size_t)NT * 4);
    int*      cnt     = (int*)alloc((size_t)NT * 4);
    int*      startp  = (int*)alloc((size_t)NT * 4);
    int*      cursor  = (int*)alloc((size_t)NT * 4);
    float*    dis     = (float*)alloc((size_t)NT * 4);
    int*      bsum    = (int*)alloc(4096);
    int*      bpre    = (int*)alloc(4096);
    int*      csrc    = (int*)alloc((size_t)E * 4);
    ushort_t* Wt      = (ushort_t*)alloc((size_t)DEPTH * H_DIM * H_DIM * 2);  // fp16
    float*    partial = (float*)alloc((size_t)(NT / 64) * H_DIM * 4);
    float*    partial2= (float*)alloc((size_t)64 * H_DIM * 4);
    float*    pooled  = (float*)alloc((size_t)B * H_DIM * 4);
    if (off > ws_size) return;   // workspace too small: fail visibly

    const int* esrc = eidx;
    const int* edst = eidx + E;

    dim3 blk(256);
    int gNT = (NT + 255) / 256;
    int gE  = (E + 255) / 256;
    int nb  = gNT;               // 512 scan blocks

    hipMemsetAsync(cnt, 0, (size_t)NT * 4, stream);

    k_gather_x0<<<gNT, blk, 0, stream>>>(sst, mask, x0, NT, Nn, F);
    k_count<<<gE, blk, 0, stream>>>(edst, cnt, E);
    k_dis<<<gNT, blk, 0, stream>>>(cnt, dis, NT);
    k_scan_block<<<nb, blk, 0, stream>>>(cnt, bsum, NT);
    k_scan_top<<<1, 512, 0, stream>>>(bsum, bpre, nb);
    k_scan_scatter<<<nb, blk, 0, stream>>>(cnt, bpre, startp, cursor, NT);
    k_fill<<<gE, blk, 0, stream>>>(esrc, edst, cursor, csrc, E);
    k_prepW<<<(DEPTH * H_DIM * H_DIM + 255) / 256, blk, 0, stream>>>(Ws, Wt, DEPTH * H_DIM * H_DIM);

    // layer 1: scalar -> H (fp16 residual stream)
    k_agg0<<<gNT, blk, 0, stream>>>(x0, startp, cnt, csrc, dis, y0, NT);
    k_expand<<<(NT * 64 + 255) / 256, blk, 0, stream>>>(x0, y0, W1, b1, xh, NT);

    // layers 2..9: z = xh@W (fp8 out), then aggregate+bias+leaky+residual into xh
    for (int l = 0; l < DEPTH; l++) {
        k_gemm<<<512, blk, 0, stream>>>(xh, Wt + (size_t)l * H_DIM * H_DIM, zbuf, NT);
        k_aggres<<<NT / 4, blk, 0, stream>>>(zbuf, startp, cnt, csrc, dis,
                                             bs + (size_t)l * H_DIM, xh, NT);
    }

    // pool + head: 2048 -> 32 -> 2
    int pblocks = NT / 64;                 // 2048
    int chunksPerBatch = 16;
    int rowsPerChunk = (pblocks / B) / chunksPerBatch;   // 64
    k_pool1<<<pblocks, blk, 0, stream>>>(xh, partial);
    k_pool2<<<B * chunksPerBatch, blk, 0, stream>>>(partial, partial2, rowsPerChunk);
    k_pool3<<<B, blk, 0, stream>>>(partial2, pooled, chunksPerBatch, 1.0f / (float)Nn);
    k_head<<<B, blk, 0, stream>>>(pooled, Wh, bh, (float*)d_out);
}

// Round 11
// 936.952 us; speedup vs baseline: 1.0676x; 1.0676x over previous
//
#include <hip/hip_runtime.h>

typedef unsigned short ushort_t;
typedef _Float16 f16x8 __attribute__((ext_vector_type(8)));
typedef float f32x4 __attribute__((ext_vector_type(4)));
typedef float f32x2 __attribute__((ext_vector_type(2)));

#define H_DIM 256
#define OUT_DIM 256

__device__ inline float lrelu(float v) { return v > 0.f ? v : 0.01f * v; }

__device__ inline unsigned short f2h(float f) {
    _Float16 h = (_Float16)f;
    unsigned short u;
    __builtin_memcpy(&u, &h, 2);
    return u;
}

__device__ inline float h2f(unsigned short u) {
    _Float16 h;
    __builtin_memcpy(&h, &u, 2);
    return (float)h;
}

// ---------- prep kernels ----------

__global__ void k_gather_x0(const float* __restrict__ sst, const int* __restrict__ mask,
                            float* __restrict__ x0, int NT, int Nn, int F) {
    int v = blockIdx.x * 256 + threadIdx.x;
    if (v < NT) {
        int b = v / Nn;
        int i = v - b * Nn;
        x0[v] = sst[(size_t)b * F + mask[i]];
    }
}

// count + record each edge's rank within its dst bucket (coalesced store)
__global__ void k_count(const int* __restrict__ dst, int* __restrict__ cnt,
                        int* __restrict__ rank, int E) {
    int e = blockIdx.x * 256 + threadIdx.x;
    if (e < E) rank[e] = atomicAdd(&cnt[dst[e]], 1);
}

__global__ void k_dis(const int* __restrict__ cnt, float* __restrict__ dis, int NT) {
    int v = blockIdx.x * 256 + threadIdx.x;
    if (v < NT) dis[v] = rsqrtf((float)cnt[v] + 1.0f);
}

__global__ void k_scan_block(const int* __restrict__ cnt, int* __restrict__ bsum, int NT) {
    __shared__ int s[256];
    int i = blockIdx.x * 256 + threadIdx.x;
    s[threadIdx.x] = (i < NT) ? cnt[i] : 0;
    __syncthreads();
    for (int o = 128; o > 0; o >>= 1) {
        if (threadIdx.x < o) s[threadIdx.x] += s[threadIdx.x + o];
        __syncthreads();
    }
    if (threadIdx.x == 0) bsum[blockIdx.x] = s[0];
}

__global__ void k_scan_top(const int* __restrict__ bsum, int* __restrict__ bpre, int nb) {
    __shared__ int s[512];
    int t = threadIdx.x;
    int v = (t < nb) ? bsum[t] : 0;
    s[t] = v;
    __syncthreads();
    for (int o = 1; o < nb; o <<= 1) {
        int add = (t >= o) ? s[t - o] : 0;
        __syncthreads();
        s[t] += add;
        __syncthreads();
    }
    if (t < nb) bpre[t] = s[t] - v;   // exclusive
}

__global__ void k_scan_scatter(const int* __restrict__ cnt, const int* __restrict__ bpre,
                               int* __restrict__ startp, int NT) {
    __shared__ int s[256];
    int t = threadIdx.x;
    int i = blockIdx.x * 256 + t;
    int v = (i < NT) ? cnt[i] : 0;
    s[t] = v;
    __syncthreads();
    for (int o = 1; o < 256; o <<= 1) {
        int add = (t >= o) ? s[t - o] : 0;
        __syncthreads();
        s[t] += add;
        __syncthreads();
    }
    int excl = s[t] - v + bpre[blockIdx.x];
    if (i < NT) startp[i] = excl;
}

// fill: atomic-free; one packed 8B store per edge {src, cnorm bits}
__global__ void k_fill(const int* __restrict__ src, const int* __restrict__ dst,
                       const int* __restrict__ rank, const int* __restrict__ startp,
                       const float* __restrict__ dis, int2* __restrict__ ecsr, int E) {
    int e = blockIdx.x * 256 + threadIdx.x;
    if (e < E) {
        int s = src[e], d = dst[e];
        float nw = dis[s] * dis[d];
        int p = startp[d] + rank[e];
        ecsr[p] = make_int2(s, __float_as_int(nw));
    }
}

__global__ void k_prepW(const float* __restrict__ Ws, ushort_t* __restrict__ Wt, int total) {
    int idx = blockIdx.x * 256 + threadIdx.x;
    if (idx < total) {
        int l = idx >> 16;          // layer
        int rem = idx & 65535;
        int k = rem >> 8;           // input dim
        int n = rem & 255;          // output dim
        Wt[(l << 16) + (n << 8) + k] = f2h(Ws[idx]);
    }
}

// ---------- layer 1 (scalar input) ----------

__global__ void k_agg0(const float* __restrict__ x0, const int* __restrict__ startp,
                       const int* __restrict__ cnt, const int2* __restrict__ ecsr,
                       const float* __restrict__ dis, float* __restrict__ y0, int NT) {
    int v = blockIdx.x * 256 + threadIdx.x;
    if (v >= NT) return;
    float d = dis[v];
    float acc = d * d * x0[v];
    int s = startp[v], e = s + cnt[v];
    for (int i = s; i < e; i++) {
        int2 ec = ecsr[i];
        acc += __int_as_float(ec.y) * x0[ec.x];
    }
    y0[v] = acc;
}

__global__ void k_expand(const float* __restrict__ x0, const float* __restrict__ y0,
                         const float* __restrict__ W1, const float* __restrict__ b1,
                         ushort_t* __restrict__ xh, int NT) {
    int idx = blockIdx.x * 256 + threadIdx.x;      // one float4-worth each, NT*64 total
    int v = idx >> 6;
    int q = idx & 63;
    if (v >= NT) return;
    float xv = x0[v], yv = y0[v];
    float4 w = ((const float4*)W1)[q];
    float4 b = ((const float4*)b1)[q];
    ushort4 o;
    o.x = f2h(xv + lrelu(yv * w.x + b.x));
    o.y = f2h(xv + lrelu(yv * w.y + b.y));
    o.z = f2h(xv + lrelu(yv * w.z + b.z));
    o.w = f2h(xv + lrelu(yv * w.w + b.w));
    ((ushort4*)xh)[(size_t)v * 64 + q] = o;
}

// ---------- GEMM: z = xh @ W (fp16 MFMA, f32 acc, fp8 e4m3 out) ----------
// W held in REGISTERS (loaded once/block from L2); A staged once per 64-row tile
// for the FULL K=256 with XOR-swizzled LDS ([row][col^((row&7)<<4)]).
// Block: 256 thr = 4 waves, wave w owns cols [w*64, w*64+64) of all 64 rows.
// Grid-stride over NT/64 tiles. One barrier pair per tile.

__global__ __launch_bounds__(256) void k_gemm(const ushort_t* __restrict__ xh,
                                              const ushort_t* __restrict__ Wt,
                                              unsigned char* __restrict__ z, int NT) {
    __shared__ __align__(16) char AsRaw[64 * 512];    // 32 KB: 64 rows x 512B (swizzled)
    __shared__ __align__(16) char Rep[4][4096];       // 16 KB: per-wave fp8 repack
    int tid = threadIdx.x;
    int wave = tid >> 6, lane = tid & 63;
    int rl = lane & 15, hi = lane >> 4;               // hi in 0..3

    // ---- W fragments into registers: wave owns n-cols [wave*64, +64) ----
    f16x8 bf[4][8];
    #pragma unroll
    for (int ni = 0; ni < 4; ni++)
        #pragma unroll
        for (int c = 0; c < 8; c++)
            bf[ni][c] = *(const f16x8*)(Wt + (size_t)(wave * 64 + ni * 16 + rl) * 256
                                        + c * 32 + hi * 8);

    int ntiles = NT / 64;
    for (int t = blockIdx.x; t < ntiles; t += gridDim.x) {
        size_t rowbase = (size_t)t * 64;

        // ---- stage A tile: 64 rows x 256 fp16, swizzled write ----
        #pragma unroll
        for (int p = 0; p < 8; p++) {
            int idx = p * 256 + tid;          // 2048 chunks of 16B
            int row = idx >> 5;
            int colb = (idx & 31) * 16;
            uint4 vsrc = *(const uint4*)(xh + (rowbase + row) * H_DIM + (idx & 31) * 8);
            *(uint4*)(AsRaw + row * 512 + (colb ^ ((row & 7) << 4))) = vsrc;
        }
        __syncthreads();

        // ---- MFMA: 8 k-chunks x (4 mi x 4 ni) ----
        f32x4 acc[4][4];
        #pragma unroll
        for (int mi = 0; mi < 4; mi++)
            #pragma unroll
            for (int ni = 0; ni < 4; ni++)
                acc[mi][ni] = (f32x4){0.f, 0.f, 0.f, 0.f};

        #pragma unroll
        for (int c = 0; c < 8; c++) {
            f16x8 af[4];
            #pragma unroll
            for (int mi = 0; mi < 4; mi++) {
                int row = mi * 16 + rl;
                int colb = c * 64 + hi * 16;
                af[mi] = *(const f16x8*)(AsRaw + row * 512 + (colb ^ ((row & 7) << 4)));
            }
            #pragma unroll
            for (int mi = 0; mi < 4; mi++)
                #pragma unroll
                for (int ni = 0; ni < 4; ni++)
                    acc[mi][ni] = __builtin_amdgcn_mfma_f32_16x16x32_f16(
                        af[mi], bf[ni][c], acc[mi][ni], 0, 0, 0);
        }
        __syncthreads();   // As free for next tile's stage

        // ---- epilogue: fp8 pack -> per-wave LDS slice -> coalesced stores ----
        char* slice = &Rep[wave][0];
        #pragma unroll
        for (int mi = 0; mi < 4; mi++)
            #pragma unroll
            for (int ni = 0; ni < 4; ni++)
                #pragma unroll
                for (int r = 0; r < 4; r++) {
                    float vv = acc[mi][ni][r];
                    int pk = __builtin_amdgcn_cvt_pk_fp8_f32(vv, vv, 0, false);
                    slice[(mi * 16 + hi * 4 + r) * 64 + ni * 16 + rl] = (char)(pk & 0xFF);
                }
        #pragma unroll
        for (int p = 0; p < 4; p++) {
            uint4 val = *(const uint4*)(slice + p * 1024 + lane * 16);
            int lrow = p * 16 + (lane >> 2);
            int lcolb = (lane & 3) * 16;
            *(uint4*)(z + (rowbase + lrow) * 256 + wave * 64 + lcolb) = val;
        }
    }
}

// ---------- aggregate + bias + leaky + residual (in-place fp16 xh update) ----------
// One 64-lane wave per node; fp8 z rows (256B, 1 dword/lane), unroll-4 gather.
// Packed ecsr stream: 8B/edge contiguous {src, weight}.

__global__ void k_aggres(const unsigned char* __restrict__ z, const int* __restrict__ startp,
                         const int* __restrict__ cnt, const int2* __restrict__ ecsr,
                         const float* __restrict__ dis, const float* __restrict__ bias,
                         ushort_t* __restrict__ xh, int NT) {
    int gid = blockIdx.x * blockDim.x + threadIdx.x;
    int v = gid >> 6;
    int lane = threadIdx.x & 63;
    if (v >= NT) return;

    // hoisted independent loads (in flight during gather)
    float d = dis[v];
    int s = startp[v], e = s + cnt[v];
    unsigned int a = *(const unsigned int*)(z + (size_t)v * 256 + lane * 4);
    ushort4 xr = *(const ushort4*)(xh + (size_t)v * H_DIM + lane * 4);
    float4 bv = *(const float4*)(bias + lane * 4);

    float sn = d * d;
    f32x2 a01 = __builtin_amdgcn_cvt_pk_f32_fp8(a, false);
    f32x2 a23 = __builtin_amdgcn_cvt_pk_f32_fp8(a, true);
    float acc0 = sn * a01[0], acc1 = sn * a01[1];
    float acc2 = sn * a23[0], acc3 = sn * a23[1];

    int i = s;
    for (; i + 4 <= e; i += 4) {
        int2 e0 = ecsr[i], e1 = ecsr[i + 1], e2 = ecsr[i + 2], e3 = ecsr[i + 3];
        float w0 = __int_as_float(e0.y), w1 = __int_as_float(e1.y);
        float w2 = __int_as_float(e2.y), w3 = __int_as_float(e3.y);
        unsigned int b0 = *(const unsigned int*)(z + (size_t)e0.x * 256 + lane * 4);
        unsigned int b1 = *(const unsigned int*)(z + (size_t)e1.x * 256 + lane * 4);
        unsigned int b2 = *(const unsigned int*)(z + (size_t)e2.x * 256 + lane * 4);
        unsigned int b3 = *(const unsigned int*)(z + (size_t)e3.x * 256 + lane * 4);
        f32x2 p0 = __builtin_amdgcn_cvt_pk_f32_fp8(b0, false);
        f32x2 q0 = __builtin_amdgcn_cvt_pk_f32_fp8(b0, true);
        f32x2 p1 = __builtin_amdgcn_cvt_pk_f32_fp8(b1, false);
        f32x2 q1 = __builtin_amdgcn_cvt_pk_f32_fp8(b1, true);
        f32x2 p2 = __builtin_amdgcn_cvt_pk_f32_fp8(b2, false);
        f32x2 q2 = __builtin_amdgcn_cvt_pk_f32_fp8(b2, true);
        f32x2 p3 = __builtin_amdgcn_cvt_pk_f32_fp8(b3, false);
        f32x2 q3 = __builtin_amdgcn_cvt_pk_f32_fp8(b3, true);
        acc0 += w0 * p0[0] + w1 * p1[0] + w2 * p2[0] + w3 * p3[0];
        acc1 += w0 * p0[1] + w1 * p1[1] + w2 * p2[1] + w3 * p3[1];
        acc2 += w0 * q0[0] + w1 * q1[0] + w2 * q2[0] + w3 * q3[0];
        acc3 += w0 * q0[1] + w1 * q1[1] + w2 * q2[1] + w3 * q3[1];
    }
    for (; i < e; i++) {
        int2 ec = ecsr[i];
        float nw = __int_as_float(ec.y);
        unsigned int b = *(const unsigned int*)(z + (size_t)ec.x * 256 + lane * 4);
        f32x2 p = __builtin_amdgcn_cvt_pk_f32_fp8(b, false);
        f32x2 q = __builtin_amdgcn_cvt_pk_f32_fp8(b, true);
        acc0 += nw * p[0]; acc1 += nw * p[1];
        acc2 += nw * q[0]; acc3 += nw * q[1];
    }

    ushort4 o;
    o.x = f2h(h2f(xr.x) + lrelu(acc0 + bv.x));
    o.y = f2h(h2f(xr.y) + lrelu(acc1 + bv.y));
    o.z = f2h(h2f(xr.z) + lrelu(acc2 + bv.z));
    o.w = f2h(h2f(xr.w) + lrelu(acc3 + bv.w));
    *(ushort4*)(xh + (size_t)v * H_DIM + lane * 4) = o;
}

// ---------- pooling (3-stage tree) + head ----------

__global__ void k_pool1(const ushort_t* __restrict__ xh, float* __restrict__ partial) {
    __shared__ float s[4][256];
    int t = threadIdx.x;
    int w = t >> 6, lane = t & 63;
    size_t nodebase = (size_t)blockIdx.x * 64;
    float4 acc = make_float4(0.f, 0.f, 0.f, 0.f);
    for (int i = 0; i < 16; i++) {
        size_t node = nodebase + i * 4 + w;
        ushort4 v = *(const ushort4*)(xh + node * H_DIM + lane * 4);
        acc.x += h2f(v.x); acc.y += h2f(v.y); acc.z += h2f(v.z); acc.w += h2f(v.w);
    }
    *(float4*)&s[w][lane * 4] = acc;
    __syncthreads();
    float sum = s[0][t] + s[1][t] + s[2][t] + s[3][t];
    partial[(size_t)blockIdx.x * H_DIM + t] = sum;
}

__global__ void k_pool2(const float* __restrict__ partial, float* __restrict__ partial2,
                        int rowsPerChunk) {
    int blk = blockIdx.x, t = threadIdx.x;
    size_t rowbase = (size_t)blk * rowsPerChunk;
    float s = 0.f;
    for (int j = 0; j < rowsPerChunk; j++)
        s += partial[(rowbase + j) * H_DIM + t];
    partial2[(size_t)blk * H_DIM + t] = s;
}

__global__ void k_pool3(const float* __restrict__ partial2, float* __restrict__ pooled,
                        int chunksPerBatch, float inv) {
    int b = blockIdx.x, t = threadIdx.x;
    float s = 0.f;
    for (int j = 0; j < chunksPerBatch; j++)
        s += partial2[((size_t)b * chunksPerBatch + j) * H_DIM + t];
    pooled[b * H_DIM + t] = s * inv;
}

__global__ void k_head(const float* __restrict__ pooled, const float* __restrict__ Wh,
                       const float* __restrict__ bh, float* __restrict__ out) {
    int b = blockIdx.x, o = threadIdx.x;
    float acc = bh[o];
    for (int h = 0; h < H_DIM; h++) acc += pooled[b * H_DIM + h] * Wh[h * OUT_DIM + o];
    out[b * OUT_DIM + o] = acc;
}

// ---------- host ----------

extern "C" void kernel_launch(void* const* d_in, const int* in_sizes, int n_in,
                              void* d_out, int out_size, void* d_ws, size_t ws_size,
                              hipStream_t stream) {
    const float* sst  = (const float*)d_in[0];
    const int*   mask = (const int*)d_in[1];
    const int*   eidx = (const int*)d_in[2];
    const float* W1   = (const float*)d_in[3];
    const float* b1   = (const float*)d_in[4];
    const float* Ws   = (const float*)d_in[5];
    const float* bs   = (const float*)d_in[6];
    const float* Wh   = (const float*)d_in[7];
    const float* bh   = (const float*)d_in[8];

    const int B  = out_size / OUT_DIM;               // 2
    const int Nn = in_sizes[1];                      // 65536
    const int E  = in_sizes[2] / 2;                  // 1048576
    const int F  = in_sizes[0] / B;                  // 686364
    const int DEPTH = in_sizes[5] / (H_DIM * H_DIM); // 8
    const int NT = B * Nn;                           // 131072

    // workspace carve-up (256B aligned) — total ~125 MB
    size_t off = 0;
    char* base = (char*)d_ws;
    auto alloc = [&](size_t bytes) -> void* {
        void* p = base + off;
        off += (bytes + 255) & ~(size_t)255;
        return p;
    };
    ushort_t*      xh      = (ushort_t*)alloc((size_t)NT * H_DIM * 2);  // 67.1 MB fp16 residual
    unsigned char* zbuf    = (unsigned char*)alloc((size_t)NT * 256);   // 33.5 MB fp8
    float*    x0      = (float*)alloc((size_t)NT * 4);
    float*    y0      = (float*)alloc((size_t)NT * 4);
    int*      cnt     = (int*)alloc((size_t)NT * 4);
    int*      startp  = (int*)alloc((size_t)NT * 4);
    float*    dis     = (float*)alloc((size_t)NT * 4);
    int*      bsum    = (int*)alloc(4096);
    int*      bpre    = (int*)alloc(4096);
    int*      rank    = (int*)alloc((size_t)E * 4);                     // 4 MB
    int2*     ecsr    = (int2*)alloc((size_t)E * 8);                    // 8 MB
    ushort_t* Wt      = (ushort_t*)alloc((size_t)DEPTH * H_DIM * H_DIM * 2);  // 1 MB fp16
    float*    partial = (float*)alloc((size_t)(NT / 64) * H_DIM * 4);
    float*    partial2= (float*)alloc((size_t)64 * H_DIM * 4);
    float*    pooled  = (float*)alloc((size_t)B * H_DIM * 4);
    if (off > ws_size) return;   // workspace too small: fail visibly

    const int* esrc = eidx;
    const int* edst = eidx + E;

    dim3 blk(256);
    int gNT = (NT + 255) / 256;
    int gE  = (E + 255) / 256;
    int nb  = gNT;               // 512 scan blocks

    hipMemsetAsync(cnt, 0, (size_t)NT * 4, stream);

    k_gather_x0<<<gNT, blk, 0, stream>>>(sst, mask, x0, NT, Nn, F);
    k_count<<<gE, blk, 0, stream>>>(edst, cnt, rank, E);
    k_dis<<<gNT, blk, 0, stream>>>(cnt, dis, NT);
    k_scan_block<<<nb, blk, 0, stream>>>(cnt, bsum, NT);
    k_scan_top<<<1, 512, 0, stream>>>(bsum, bpre, nb);
    k_scan_scatter<<<nb, blk, 0, stream>>>(cnt, bpre, startp, NT);
    k_fill<<<gE, blk, 0, stream>>>(esrc, edst, rank, startp, dis, ecsr, E);
    k_prepW<<<(DEPTH * H_DIM * H_DIM + 255) / 256, blk, 0, stream>>>(Ws, Wt, DEPTH * H_DIM * H_DIM);

    // layer 1: scalar -> H (fp16 residual stream)
    k_agg0<<<gNT, blk, 0, stream>>>(x0, startp, cnt, ecsr, dis, y0, NT);
    k_expand<<<(NT * 64 + 255) / 256, blk, 0, stream>>>(x0, y0, W1, b1, xh, NT);

    // layers 2..9: z = xh@W (fp8 out), then aggregate+bias+leaky+residual into xh
    for (int l = 0; l < DEPTH; l++) {
        k_gemm<<<512, blk, 0, stream>>>(xh, Wt + (size_t)l * H_DIM * H_DIM, zbuf, NT);
        k_aggres<<<NT / 4, blk, 0, stream>>>(zbuf, startp, cnt, ecsr, dis,
                                             bs + (size_t)l * H_DIM, xh, NT);
    }

    // pool + head: 2048 -> 32 -> 2
    int pblocks = NT / 64;                 // 2048
    int chunksPerBatch = 16;
    int rowsPerChunk = (pblocks / B) / chunksPerBatch;   // 64
    k_pool1<<<pblocks, blk, 0, stream>>>(xh, partial);
    k_pool2<<<B * chunksPerBatch, blk, 0, stream>>>(partial, partial2, rowsPerChunk);
    k_pool3<<<B, blk, 0, stream>>>(partial2, pooled, chunksPerBatch, 1.0f / (float)Nn);
    k_head<<<B, blk, 0, stream>>>(pooled, Wh, bh, (float*)d_out);
}

// Round 12
// 878.077 us; speedup vs baseline: 1.1392x; 1.0671x over previous
//
#include <hip/hip_runtime.h>

typedef unsigned short ushort_t;
typedef _Float16 f16x8 __attribute__((ext_vector_type(8)));
typedef float f32x4 __attribute__((ext_vector_type(4)));
typedef float f32x2 __attribute__((ext_vector_type(2)));

#define H_DIM 256
#define OUT_DIM 256

__device__ inline float lrelu(float v) { return v > 0.f ? v : 0.01f * v; }

__device__ inline unsigned short f2h(float f) {
    _Float16 h = (_Float16)f;
    unsigned short u;
    __builtin_memcpy(&u, &h, 2);
    return u;
}

__device__ inline float h2f(unsigned short u) {
    _Float16 h;
    __builtin_memcpy(&h, &u, 2);
    return (float)h;
}

// ---------- prep kernels ----------

__global__ void k_gather_x0(const float* __restrict__ sst, const int* __restrict__ mask,
                            float* __restrict__ x0, int NT, int Nn, int F) {
    int v = blockIdx.x * 256 + threadIdx.x;
    if (v < NT) {
        int b = v / Nn;
        int i = v - b * Nn;
        x0[v] = sst[(size_t)b * F + mask[i]];
    }
}

// count + record each edge's rank within its dst bucket (coalesced store)
__global__ void k_count(const int* __restrict__ dst, int* __restrict__ cnt,
                        int* __restrict__ rank, int E) {
    int e = blockIdx.x * 256 + threadIdx.x;
    if (e < E) rank[e] = atomicAdd(&cnt[dst[e]], 1);
}

__global__ void k_dis(const int* __restrict__ cnt, float* __restrict__ dis, int NT) {
    int v = blockIdx.x * 256 + threadIdx.x;
    if (v < NT) dis[v] = rsqrtf((float)cnt[v] + 1.0f);
}

__global__ void k_scan_block(const int* __restrict__ cnt, int* __restrict__ bsum, int NT) {
    __shared__ int s[256];
    int i = blockIdx.x * 256 + threadIdx.x;
    s[threadIdx.x] = (i < NT) ? cnt[i] : 0;
    __syncthreads();
    for (int o = 128; o > 0; o >>= 1) {
        if (threadIdx.x < o) s[threadIdx.x] += s[threadIdx.x + o];
        __syncthreads();
    }
    if (threadIdx.x == 0) bsum[blockIdx.x] = s[0];
}

__global__ void k_scan_top(const int* __restrict__ bsum, int* __restrict__ bpre, int nb) {
    __shared__ int s[512];
    int t = threadIdx.x;
    int v = (t < nb) ? bsum[t] : 0;
    s[t] = v;
    __syncthreads();
    for (int o = 1; o < nb; o <<= 1) {
        int add = (t >= o) ? s[t - o] : 0;
        __syncthreads();
        s[t] += add;
        __syncthreads();
    }
    if (t < nb) bpre[t] = s[t] - v;   // exclusive
}

__global__ void k_scan_scatter(const int* __restrict__ cnt, const int* __restrict__ bpre,
                               int* __restrict__ startp, int NT) {
    __shared__ int s[256];
    int t = threadIdx.x;
    int i = blockIdx.x * 256 + t;
    int v = (i < NT) ? cnt[i] : 0;
    s[t] = v;
    __syncthreads();
    for (int o = 1; o < 256; o <<= 1) {
        int add = (t >= o) ? s[t - o] : 0;
        __syncthreads();
        s[t] += add;
        __syncthreads();
    }
    int excl = s[t] - v + bpre[blockIdx.x];
    if (i < NT) startp[i] = excl;
}

// fill: atomic-free; one packed 8B store per edge {src, cnorm bits}
__global__ void k_fill(const int* __restrict__ src, const int* __restrict__ dst,
                       const int* __restrict__ rank, const int* __restrict__ startp,
                       const float* __restrict__ dis, int2* __restrict__ ecsr, int E) {
    int e = blockIdx.x * 256 + threadIdx.x;
    if (e < E) {
        int s = src[e], d = dst[e];
        float nw = dis[s] * dis[d];
        int p = startp[d] + rank[e];
        ecsr[p] = make_int2(s, __float_as_int(nw));
    }
}

__global__ void k_prepW(const float* __restrict__ Ws, ushort_t* __restrict__ Wt, int total) {
    int idx = blockIdx.x * 256 + threadIdx.x;
    if (idx < total) {
        int l = idx >> 16;          // layer
        int rem = idx & 65535;
        int k = rem >> 8;           // input dim
        int n = rem & 255;          // output dim
        Wt[(l << 16) + (n << 8) + k] = f2h(Ws[idx]);
    }
}

// ---------- layer 1 (scalar input) ----------

__global__ void k_agg0(const float* __restrict__ x0, const int* __restrict__ startp,
                       const int* __restrict__ cnt, const int2* __restrict__ ecsr,
                       const float* __restrict__ dis, float* __restrict__ y0, int NT) {
    int v = blockIdx.x * 256 + threadIdx.x;
    if (v >= NT) return;
    float d = dis[v];
    float acc = d * d * x0[v];
    int s = startp[v], e = s + cnt[v];
    for (int i = s; i < e; i++) {
        int2 ec = ecsr[i];
        acc += __int_as_float(ec.y) * x0[ec.x];
    }
    y0[v] = acc;
}

__global__ void k_expand(const float* __restrict__ x0, const float* __restrict__ y0,
                         const float* __restrict__ W1, const float* __restrict__ b1,
                         ushort_t* __restrict__ xh, int NT) {
    int idx = blockIdx.x * 256 + threadIdx.x;      // one float4-worth each, NT*64 total
    int v = idx >> 6;
    int q = idx & 63;
    if (v >= NT) return;
    float xv = x0[v], yv = y0[v];
    float4 w = ((const float4*)W1)[q];
    float4 b = ((const float4*)b1)[q];
    ushort4 o;
    o.x = f2h(xv + lrelu(yv * w.x + b.x));
    o.y = f2h(xv + lrelu(yv * w.y + b.y));
    o.z = f2h(xv + lrelu(yv * w.z + b.z));
    o.w = f2h(xv + lrelu(yv * w.w + b.w));
    ((ushort4*)xh)[(size_t)v * 64 + q] = o;
}

// ---------- GEMM: z = xh @ W (fp16 MFMA, f32 acc, fp8 e4m3 out) ----------
// W held in REGISTERS (loaded once/block from L2); A staged once per 64-row tile
// for the FULL K=256 with XOR-swizzled LDS ([row][col^((row&7)<<4)]).
// Block: 256 thr = 4 waves, wave w owns cols [w*64, w*64+64) of all 64 rows.
// Grid-stride over NT/64 tiles. One barrier pair per tile.

__global__ __launch_bounds__(256) void k_gemm(const ushort_t* __restrict__ xh,
                                              const ushort_t* __restrict__ Wt,
                                              unsigned char* __restrict__ z, int NT) {
    __shared__ __align__(16) char AsRaw[64 * 512];    // 32 KB: 64 rows x 512B (swizzled)
    __shared__ __align__(16) char Rep[4][4096];       // 16 KB: per-wave fp8 repack
    int tid = threadIdx.x;
    int wave = tid >> 6, lane = tid & 63;
    int rl = lane & 15, hi = lane >> 4;               // hi in 0..3

    // ---- W fragments into registers: wave owns n-cols [wave*64, +64) ----
    f16x8 bf[4][8];
    #pragma unroll
    for (int ni = 0; ni < 4; ni++)
        #pragma unroll
        for (int c = 0; c < 8; c++)
            bf[ni][c] = *(const f16x8*)(Wt + (size_t)(wave * 64 + ni * 16 + rl) * 256
                                        + c * 32 + hi * 8);

    int ntiles = NT / 64;
    for (int t = blockIdx.x; t < ntiles; t += gridDim.x) {
        size_t rowbase = (size_t)t * 64;

        // ---- stage A tile: 64 rows x 256 fp16, swizzled write ----
        #pragma unroll
        for (int p = 0; p < 8; p++) {
            int idx = p * 256 + tid;          // 2048 chunks of 16B
            int row = idx >> 5;
            int colb = (idx & 31) * 16;
            uint4 vsrc = *(const uint4*)(xh + (rowbase + row) * H_DIM + (idx & 31) * 8);
            *(uint4*)(AsRaw + row * 512 + (colb ^ ((row & 7) << 4))) = vsrc;
        }
        __syncthreads();

        // ---- MFMA: 8 k-chunks x (4 mi x 4 ni) ----
        f32x4 acc[4][4];
        #pragma unroll
        for (int mi = 0; mi < 4; mi++)
            #pragma unroll
            for (int ni = 0; ni < 4; ni++)
                acc[mi][ni] = (f32x4){0.f, 0.f, 0.f, 0.f};

        #pragma unroll
        for (int c = 0; c < 8; c++) {
            f16x8 af[4];
            #pragma unroll
            for (int mi = 0; mi < 4; mi++) {
                int row = mi * 16 + rl;
                int colb = c * 64 + hi * 16;
                af[mi] = *(const f16x8*)(AsRaw + row * 512 + (colb ^ ((row & 7) << 4)));
            }
            #pragma unroll
            for (int mi = 0; mi < 4; mi++)
                #pragma unroll
                for (int ni = 0; ni < 4; ni++)
                    acc[mi][ni] = __builtin_amdgcn_mfma_f32_16x16x32_f16(
                        af[mi], bf[ni][c], acc[mi][ni], 0, 0, 0);
        }
        __syncthreads();   // As free for next tile's stage

        // ---- epilogue: fp8 pack -> per-wave LDS slice -> coalesced stores ----
        char* slice = &Rep[wave][0];
        #pragma unroll
        for (int mi = 0; mi < 4; mi++)
            #pragma unroll
            for (int ni = 0; ni < 4; ni++)
                #pragma unroll
                for (int r = 0; r < 4; r++) {
                    float vv = acc[mi][ni][r];
                    int pk = __builtin_amdgcn_cvt_pk_fp8_f32(vv, vv, 0, false);
                    slice[(mi * 16 + hi * 4 + r) * 64 + ni * 16 + rl] = (char)(pk & 0xFF);
                }
        #pragma unroll
        for (int p = 0; p < 4; p++) {
            uint4 val = *(const uint4*)(slice + p * 1024 + lane * 16);
            int lrow = p * 16 + (lane >> 2);
            int lcolb = (lane & 3) * 16;
            *(uint4*)(z + (rowbase + lrow) * 256 + wave * 64 + lcolb) = val;
        }
    }
}

// ---------- aggregate + bias + leaky + residual (in-place fp16 xh update) ----------
// One 64-lane wave per node. Neighbor metadata loaded ONCE per wave (lane k holds
// edge k), then broadcast per-edge via __shfl (ds_bpermute) — removes the
// ecsr-load -> row-load serial latency chain. Tail slots have w=0 (zero-init lanes).

__global__ void k_aggres(const unsigned char* __restrict__ z, const int* __restrict__ startp,
                         const int* __restrict__ cnt, const int2* __restrict__ ecsr,
                         const float* __restrict__ dis, const float* __restrict__ bias,
                         ushort_t* __restrict__ xh, int NT) {
    int gid = blockIdx.x * blockDim.x + threadIdx.x;
    int v = gid >> 6;
    int lane = threadIdx.x & 63;
    if (v >= NT) return;

    float d = dis[v];
    int s = startp[v], cv = cnt[v];

    // one coalesced metadata load per wave: lane k <- edge k
    int nsrc = 0;
    float nw = 0.f;
    if (lane < cv) {
        int2 ec = ecsr[s + lane];
        nsrc = ec.x;
        nw = __int_as_float(ec.y);
    }

    // hoisted independent loads (in flight during gather)
    unsigned int a = *(const unsigned int*)(z + (size_t)v * 256 + lane * 4);
    ushort4 xr = *(const ushort4*)(xh + (size_t)v * H_DIM + lane * 4);
    float4 bv = *(const float4*)(bias + lane * 4);

    float sn = d * d;
    f32x2 a01 = __builtin_amdgcn_cvt_pk_f32_fp8(a, false);
    f32x2 a23 = __builtin_amdgcn_cvt_pk_f32_fp8(a, true);
    float acc0 = sn * a01[0], acc1 = sn * a01[1];
    float acc2 = sn * a23[0], acc3 = sn * a23[1];

    int inlane = cv > 64 ? 64 : cv;
    int iters = (inlane + 3) & ~3;
    for (int k = 0; k < iters; k += 4) {
        int i0 = __shfl(nsrc, k);     float w0 = __shfl(nw, k);
        int i1 = __shfl(nsrc, k + 1); float w1 = __shfl(nw, k + 1);
        int i2 = __shfl(nsrc, k + 2); float w2 = __shfl(nw, k + 2);
        int i3 = __shfl(nsrc, k + 3); float w3 = __shfl(nw, k + 3);
        unsigned int b0 = *(const unsigned int*)(z + (size_t)i0 * 256 + lane * 4);
        unsigned int b1 = *(const unsigned int*)(z + (size_t)i1 * 256 + lane * 4);
        unsigned int b2 = *(const unsigned int*)(z + (size_t)i2 * 256 + lane * 4);
        unsigned int b3 = *(const unsigned int*)(z + (size_t)i3 * 256 + lane * 4);
        f32x2 p0 = __builtin_amdgcn_cvt_pk_f32_fp8(b0, false);
        f32x2 q0 = __builtin_amdgcn_cvt_pk_f32_fp8(b0, true);
        f32x2 p1 = __builtin_amdgcn_cvt_pk_f32_fp8(b1, false);
        f32x2 q1 = __builtin_amdgcn_cvt_pk_f32_fp8(b1, true);
        f32x2 p2 = __builtin_amdgcn_cvt_pk_f32_fp8(b2, false);
        f32x2 q2 = __builtin_amdgcn_cvt_pk_f32_fp8(b2, true);
        f32x2 p3 = __builtin_amdgcn_cvt_pk_f32_fp8(b3, false);
        f32x2 q3 = __builtin_amdgcn_cvt_pk_f32_fp8(b3, true);
        acc0 += w0 * p0[0] + w1 * p1[0] + w2 * p2[0] + w3 * p3[0];
        acc1 += w0 * p0[1] + w1 * p1[1] + w2 * p2[1] + w3 * p3[1];
        acc2 += w0 * q0[0] + w1 * q1[0] + w2 * q2[0] + w3 * q3[0];
        acc3 += w0 * q0[1] + w1 * q1[1] + w2 * q2[1] + w3 * q3[1];
    }
    // overflow fallback (deg > 64 — statistically never for Poisson(8))
    for (int k = 64; k < cv; k++) {
        int2 ec = ecsr[s + k];
        float w = __int_as_float(ec.y);
        unsigned int b = *(const unsigned int*)(z + (size_t)ec.x * 256 + lane * 4);
        f32x2 p = __builtin_amdgcn_cvt_pk_f32_fp8(b, false);
        f32x2 q = __builtin_amdgcn_cvt_pk_f32_fp8(b, true);
        acc0 += w * p[0]; acc1 += w * p[1];
        acc2 += w * q[0]; acc3 += w * q[1];
    }

    ushort4 o;
    o.x = f2h(h2f(xr.x) + lrelu(acc0 + bv.x));
    o.y = f2h(h2f(xr.y) + lrelu(acc1 + bv.y));
    o.z = f2h(h2f(xr.z) + lrelu(acc2 + bv.z));
    o.w = f2h(h2f(xr.w) + lrelu(acc3 + bv.w));
    *(ushort4*)(xh + (size_t)v * H_DIM + lane * 4) = o;
}

// ---------- pooling (3-stage tree) + head ----------

__global__ void k_pool1(const ushort_t* __restrict__ xh, float* __restrict__ partial) {
    __shared__ float s[4][256];
    int t = threadIdx.x;
    int w = t >> 6, lane = t & 63;
    size_t nodebase = (size_t)blockIdx.x * 64;
    float4 acc = make_float4(0.f, 0.f, 0.f, 0.f);
    for (int i = 0; i < 16; i++) {
        size_t node = nodebase + i * 4 + w;
        ushort4 v = *(const ushort4*)(xh + node * H_DIM + lane * 4);
        acc.x += h2f(v.x); acc.y += h2f(v.y); acc.z += h2f(v.z); acc.w += h2f(v.w);
    }
    *(float4*)&s[w][lane * 4] = acc;
    __syncthreads();
    float sum = s[0][t] + s[1][t] + s[2][t] + s[3][t];
    partial[(size_t)blockIdx.x * H_DIM + t] = sum;
}

__global__ void k_pool2(const float* __restrict__ partial, float* __restrict__ partial2,
                        int rowsPerChunk) {
    int blk = blockIdx.x, t = threadIdx.x;
    size_t rowbase = (size_t)blk * rowsPerChunk;
    float s = 0.f;
    for (int j = 0; j < rowsPerChunk; j++)
        s += partial[(rowbase + j) * H_DIM + t];
    partial2[(size_t)blk * H_DIM + t] = s;
}

__global__ void k_pool3(const float* __restrict__ partial2, float* __restrict__ pooled,
                        int chunksPerBatch, float inv) {
    int b = blockIdx.x, t = threadIdx.x;
    float s = 0.f;
    for (int j = 0; j < chunksPerBatch; j++)
        s += partial2[((size_t)b * chunksPerBatch + j) * H_DIM + t];
    pooled[b * H_DIM + t] = s * inv;
}

__global__ void k_head(const float* __restrict__ pooled, const float* __restrict__ Wh,
                       const float* __restrict__ bh, float* __restrict__ out) {
    int b = blockIdx.x, o = threadIdx.x;
    float acc = bh[o];
    for (int h = 0; h < H_DIM; h++) acc += pooled[b * H_DIM + h] * Wh[h * OUT_DIM + o];
    out[b * OUT_DIM + o] = acc;
}

// ---------- host ----------

extern "C" void kernel_launch(void* const* d_in, const int* in_sizes, int n_in,
                              void* d_out, int out_size, void* d_ws, size_t ws_size,
                              hipStream_t stream) {
    const float* sst  = (const float*)d_in[0];
    const int*   mask = (const int*)d_in[1];
    const int*   eidx = (const int*)d_in[2];
    const float* W1   = (const float*)d_in[3];
    const float* b1   = (const float*)d_in[4];
    const float* Ws   = (const float*)d_in[5];
    const float* bs   = (const float*)d_in[6];
    const float* Wh   = (const float*)d_in[7];
    const float* bh   = (const float*)d_in[8];

    const int B  = out_size / OUT_DIM;               // 2
    const int Nn = in_sizes[1];                      // 65536
    const int E  = in_sizes[2] / 2;                  // 1048576
    const int F  = in_sizes[0] / B;                  // 686364
    const int DEPTH = in_sizes[5] / (H_DIM * H_DIM); // 8
    const int NT = B * Nn;                           // 131072

    // workspace carve-up (256B aligned) — total ~125 MB
    size_t off = 0;
    char* base = (char*)d_ws;
    auto alloc = [&](size_t bytes) -> void* {
        void* p = base + off;
        off += (bytes + 255) & ~(size_t)255;
        return p;
    };
    ushort_t*      xh      = (ushort_t*)alloc((size_t)NT * H_DIM * 2);  // 67.1 MB fp16 residual
    unsigned char* zbuf    = (unsigned char*)alloc((size_t)NT * 256);   // 33.5 MB fp8
    float*    x0      = (float*)alloc((size_t)NT * 4);
    float*    y0      = (float*)alloc((size_t)NT * 4);
    int*      cnt     = (int*)alloc((size_t)NT * 4);
    int*      startp  = (int*)alloc((size_t)NT * 4);
    float*    dis     = (float*)alloc((size_t)NT * 4);
    int*      bsum    = (int*)alloc(4096);
    int*      bpre    = (int*)alloc(4096);
    int*      rank    = (int*)alloc((size_t)E * 4);                     // 4 MB
    int2*     ecsr    = (int2*)alloc((size_t)E * 8);                    // 8 MB
    ushort_t* Wt      = (ushort_t*)alloc((size_t)DEPTH * H_DIM * H_DIM * 2);  // 1 MB fp16
    float*    partial = (float*)alloc((size_t)(NT / 64) * H_DIM * 4);
    float*    partial2= (float*)alloc((size_t)64 * H_DIM * 4);
    float*    pooled  = (float*)alloc((size_t)B * H_DIM * 4);
    if (off > ws_size) return;   // workspace too small: fail visibly

    const int* esrc = eidx;
    const int* edst = eidx + E;

    dim3 blk(256);
    int gNT = (NT + 255) / 256;
    int gE  = (E + 255) / 256;
    int nb  = gNT;               // 512 scan blocks

    hipMemsetAsync(cnt, 0, (size_t)NT * 4, stream);

    k_gather_x0<<<gNT, blk, 0, stream>>>(sst, mask, x0, NT, Nn, F);
    k_count<<<gE, blk, 0, stream>>>(edst, cnt, rank, E);
    k_dis<<<gNT, blk, 0, stream>>>(cnt, dis, NT);
    k_scan_block<<<nb, blk, 0, stream>>>(cnt, bsum, NT);
    k_scan_top<<<1, 512, 0, stream>>>(bsum, bpre, nb);
    k_scan_scatter<<<nb, blk, 0, stream>>>(cnt, bpre, startp, NT);
    k_fill<<<gE, blk, 0, stream>>>(esrc, edst, rank, startp, dis, ecsr, E);
    k_prepW<<<(DEPTH * H_DIM * H_DIM + 255) / 256, blk, 0, stream>>>(Ws, Wt, DEPTH * H_DIM * H_DIM);

    // layer 1: scalar -> H (fp16 residual stream)
    k_agg0<<<gNT, blk, 0, stream>>>(x0, startp, cnt, ecsr, dis, y0, NT);
    k_expand<<<(NT * 64 + 255) / 256, blk, 0, stream>>>(x0, y0, W1, b1, xh, NT);

    // layers 2..9: z = xh@W (fp8 out), then aggregate+bias+leaky+residual into xh
    for (int l = 0; l < DEPTH; l++) {
        k_gemm<<<512, blk, 0, stream>>>(xh, Wt + (size_t)l * H_DIM * H_DIM, zbuf, NT);
        k_aggres<<<NT / 4, blk, 0, stream>>>(zbuf, startp, cnt, ecsr, dis,
                                             bs + (size_t)l * H_DIM, xh, NT);
    }

    // pool + head: 2048 -> 32 -> 2
    int pblocks = NT / 64;                 // 2048
    int chunksPerBatch = 16;
    int rowsPerChunk = (pblocks / B) / chunksPerBatch;   // 64
    k_pool1<<<pblocks, blk, 0, stream>>>(xh, partial);
    k_pool2<<<B * chunksPerBatch, blk, 0, stream>>>(partial, partial2, rowsPerChunk);
    k_pool3<<<B, blk, 0, stream>>>(partial2, pooled, chunksPerBatch, 1.0f / (float)Nn);
    k_head<<<B, blk, 0, stream>>>(pooled, Wh, bh, (float*)d_out);
}

// Round 13
// 848.964 us; speedup vs baseline: 1.1782x; 1.0343x over previous
//
#include <hip/hip_runtime.h>

typedef unsigned short ushort_t;
typedef _Float16 f16x8 __attribute__((ext_vector_type(8)));
typedef float f32x4 __attribute__((ext_vector_type(4)));
typedef float f32x2 __attribute__((ext_vector_type(2)));
typedef unsigned short us8 __attribute__((ext_vector_type(8)));

#define H_DIM 256
#define OUT_DIM 256

__device__ inline float lrelu(float v) { return v > 0.f ? v : 0.01f * v; }

__device__ inline unsigned short f2h(float f) {
    _Float16 h = (_Float16)f;
    unsigned short u;
    __builtin_memcpy(&u, &h, 2);
    return u;
}

__device__ inline float h2f(unsigned short u) {
    _Float16 h;
    __builtin_memcpy(&h, &u, 2);
    return (float)h;
}

// ---------- prep kernels ----------

__global__ void k_gather_x0(const float* __restrict__ sst, const int* __restrict__ mask,
                            float* __restrict__ x0, int NT, int Nn, int F) {
    int v = blockIdx.x * 256 + threadIdx.x;
    if (v < NT) {
        int b = v / Nn;
        int i = v - b * Nn;
        x0[v] = sst[(size_t)b * F + mask[i]];
    }
}

// count + record each edge's rank within its dst bucket (coalesced store)
__global__ void k_count(const int* __restrict__ dst, int* __restrict__ cnt,
                        int* __restrict__ rank, int E) {
    int e = blockIdx.x * 256 + threadIdx.x;
    if (e < E) rank[e] = atomicAdd(&cnt[dst[e]], 1);
}

__global__ void k_dis(const int* __restrict__ cnt, float* __restrict__ dis, int NT) {
    int v = blockIdx.x * 256 + threadIdx.x;
    if (v < NT) dis[v] = rsqrtf((float)cnt[v] + 1.0f);
}

__global__ void k_scan_block(const int* __restrict__ cnt, int* __restrict__ bsum, int NT) {
    __shared__ int s[256];
    int i = blockIdx.x * 256 + threadIdx.x;
    s[threadIdx.x] = (i < NT) ? cnt[i] : 0;
    __syncthreads();
    for (int o = 128; o > 0; o >>= 1) {
        if (threadIdx.x < o) s[threadIdx.x] += s[threadIdx.x + o];
        __syncthreads();
    }
    if (threadIdx.x == 0) bsum[blockIdx.x] = s[0];
}

__global__ void k_scan_top(const int* __restrict__ bsum, int* __restrict__ bpre, int nb) {
    __shared__ int s[512];
    int t = threadIdx.x;
    int v = (t < nb) ? bsum[t] : 0;
    s[t] = v;
    __syncthreads();
    for (int o = 1; o < nb; o <<= 1) {
        int add = (t >= o) ? s[t - o] : 0;
        __syncthreads();
        s[t] += add;
        __syncthreads();
    }
    if (t < nb) bpre[t] = s[t] - v;   // exclusive
}

__global__ void k_scan_scatter(const int* __restrict__ cnt, const int* __restrict__ bpre,
                               int* __restrict__ startp, int NT) {
    __shared__ int s[256];
    int t = threadIdx.x;
    int i = blockIdx.x * 256 + t;
    int v = (i < NT) ? cnt[i] : 0;
    s[t] = v;
    __syncthreads();
    for (int o = 1; o < 256; o <<= 1) {
        int add = (t >= o) ? s[t - o] : 0;
        __syncthreads();
        s[t] += add;
        __syncthreads();
    }
    int excl = s[t] - v + bpre[blockIdx.x];
    if (i < NT) startp[i] = excl;
}

// fill: atomic-free; one packed 8B store per edge {src, cnorm bits}
__global__ void k_fill(const int* __restrict__ src, const int* __restrict__ dst,
                       const int* __restrict__ rank, const int* __restrict__ startp,
                       const float* __restrict__ dis, int2* __restrict__ ecsr, int E) {
    int e = blockIdx.x * 256 + threadIdx.x;
    if (e < E) {
        int s = src[e], d = dst[e];
        float nw = dis[s] * dis[d];
        int p = startp[d] + rank[e];
        ecsr[p] = make_int2(s, __float_as_int(nw));
    }
}

__global__ void k_prepW(const float* __restrict__ Ws, ushort_t* __restrict__ Wt, int total) {
    int idx = blockIdx.x * 256 + threadIdx.x;
    if (idx < total) {
        int l = idx >> 16;          // layer
        int rem = idx & 65535;
        int k = rem >> 8;           // input dim
        int n = rem & 255;          // output dim
        Wt[(l << 16) + (n << 8) + k] = f2h(Ws[idx]);
    }
}

// ---------- layer 1 (scalar input) ----------

__global__ void k_agg0(const float* __restrict__ x0, const int* __restrict__ startp,
                       const int* __restrict__ cnt, const int2* __restrict__ ecsr,
                       const float* __restrict__ dis, float* __restrict__ y0, int NT) {
    int v = blockIdx.x * 256 + threadIdx.x;
    if (v >= NT) return;
    float d = dis[v];
    float acc = d * d * x0[v];
    int s = startp[v], e = s + cnt[v];
    for (int i = s; i < e; i++) {
        int2 ec = ecsr[i];
        acc += __int_as_float(ec.y) * x0[ec.x];
    }
    y0[v] = acc;
}

__global__ void k_expand(const float* __restrict__ x0, const float* __restrict__ y0,
                         const float* __restrict__ W1, const float* __restrict__ b1,
                         ushort_t* __restrict__ xh, int NT) {
    int idx = blockIdx.x * 256 + threadIdx.x;      // one float4-worth each, NT*64 total
    int v = idx >> 6;
    int q = idx & 63;
    if (v >= NT) return;
    float xv = x0[v], yv = y0[v];
    float4 w = ((const float4*)W1)[q];
    float4 b = ((const float4*)b1)[q];
    ushort4 o;
    o.x = f2h(xv + lrelu(yv * w.x + b.x));
    o.y = f2h(xv + lrelu(yv * w.y + b.y));
    o.z = f2h(xv + lrelu(yv * w.z + b.z));
    o.w = f2h(xv + lrelu(yv * w.w + b.w));
    ((ushort4*)xh)[(size_t)v * 64 + q] = o;
}

// ---------- GEMM: z = xh @ W (fp16 MFMA, f32 acc, fp8 e4m3 out) ----------
// W held in REGISTERS (loaded once/block from L2); A staged once per 64-row tile
// for the FULL K=256 with XOR-swizzled LDS ([row][col^((row&7)<<4)]).
// Block: 256 thr = 4 waves, wave w owns cols [w*64, w*64+64) of all 64 rows.
// Grid-stride over NT/64 tiles. One barrier pair per tile.

__global__ __launch_bounds__(256) void k_gemm(const ushort_t* __restrict__ xh,
                                              const ushort_t* __restrict__ Wt,
                                              unsigned char* __restrict__ z, int NT) {
    __shared__ __align__(16) char AsRaw[64 * 512];    // 32 KB: 64 rows x 512B (swizzled)
    __shared__ __align__(16) char Rep[4][4096];       // 16 KB: per-wave fp8 repack
    int tid = threadIdx.x;
    int wave = tid >> 6, lane = tid & 63;
    int rl = lane & 15, hi = lane >> 4;               // hi in 0..3

    // ---- W fragments into registers: wave owns n-cols [wave*64, +64) ----
    f16x8 bf[4][8];
    #pragma unroll
    for (int ni = 0; ni < 4; ni++)
        #pragma unroll
        for (int c = 0; c < 8; c++)
            bf[ni][c] = *(const f16x8*)(Wt + (size_t)(wave * 64 + ni * 16 + rl) * 256
                                        + c * 32 + hi * 8);

    int ntiles = NT / 64;
    for (int t = blockIdx.x; t < ntiles; t += gridDim.x) {
        size_t rowbase = (size_t)t * 64;

        // ---- stage A tile: 64 rows x 256 fp16, swizzled write ----
        #pragma unroll
        for (int p = 0; p < 8; p++) {
            int idx = p * 256 + tid;          // 2048 chunks of 16B
            int row = idx >> 5;
            int colb = (idx & 31) * 16;
            uint4 vsrc = *(const uint4*)(xh + (rowbase + row) * H_DIM + (idx & 31) * 8);
            *(uint4*)(AsRaw + row * 512 + (colb ^ ((row & 7) << 4))) = vsrc;
        }
        __syncthreads();

        // ---- MFMA: 8 k-chunks x (4 mi x 4 ni) ----
        f32x4 acc[4][4];
        #pragma unroll
        for (int mi = 0; mi < 4; mi++)
            #pragma unroll
            for (int ni = 0; ni < 4; ni++)
                acc[mi][ni] = (f32x4){0.f, 0.f, 0.f, 0.f};

        #pragma unroll
        for (int c = 0; c < 8; c++) {
            f16x8 af[4];
            #pragma unroll
            for (int mi = 0; mi < 4; mi++) {
                int row = mi * 16 + rl;
                int colb = c * 64 + hi * 16;
                af[mi] = *(const f16x8*)(AsRaw + row * 512 + (colb ^ ((row & 7) << 4)));
            }
            #pragma unroll
            for (int mi = 0; mi < 4; mi++)
                #pragma unroll
                for (int ni = 0; ni < 4; ni++)
                    acc[mi][ni] = __builtin_amdgcn_mfma_f32_16x16x32_f16(
                        af[mi], bf[ni][c], acc[mi][ni], 0, 0, 0);
        }
        __syncthreads();   // As free for next tile's stage

        // ---- epilogue: fp8 pack -> per-wave LDS slice -> coalesced stores ----
        char* slice = &Rep[wave][0];
        #pragma unroll
        for (int mi = 0; mi < 4; mi++)
            #pragma unroll
            for (int ni = 0; ni < 4; ni++)
                #pragma unroll
                for (int r = 0; r < 4; r++) {
                    float vv = acc[mi][ni][r];
                    int pk = __builtin_amdgcn_cvt_pk_fp8_f32(vv, vv, 0, false);
                    slice[(mi * 16 + hi * 4 + r) * 64 + ni * 16 + rl] = (char)(pk & 0xFF);
                }
        #pragma unroll
        for (int p = 0; p < 4; p++) {
            uint4 val = *(const uint4*)(slice + p * 1024 + lane * 16);
            int lrow = p * 16 + (lane >> 2);
            int lcolb = (lane & 3) * 16;
            *(uint4*)(z + (rowbase + lrow) * 256 + wave * 64 + lcolb) = val;
        }
    }
}

// ---------- aggregate + bias + leaky + residual (in-place fp16 xh update) ----------
// TWO nodes per wave: half-wave (32 lanes x 8B) covers one 256B fp8 row.
// Metadata loaded once (lane h*32+k holds edge k of node pair[h]); per-edge
// broadcast via one shfl serving both halves. 4-unroll -> 8 rows in flight/wave.

__global__ void k_aggres(const unsigned char* __restrict__ z, const int* __restrict__ startp,
                         const int* __restrict__ cnt, const int2* __restrict__ ecsr,
                         const float* __restrict__ dis, const float* __restrict__ bias,
                         ushort_t* __restrict__ xh, int NT) {
    int tid = threadIdx.x;
    int wave = tid >> 6, lane = tid & 63;
    int h = lane >> 5, hl = lane & 31;
    int v = blockIdx.x * 8 + wave * 2 + h;
    if (v >= NT) return;

    float d = dis[v];
    int s = startp[v], cv = cnt[v];

    // metadata: lane h*32+k <- edge k of this half's node (one coalesced load)
    int nsrc = 0;
    float nw = 0.f;
    if (hl < cv) {
        int2 ec = ecsr[s + hl];
        nsrc = ec.x;
        nw = __int_as_float(ec.y);
    }

    // wave-uniform iteration bound = max of both halves' degrees
    int cv0 = __shfl(cv, 0);
    int cv1 = __shfl(cv, 32);
    int cvmax = cv0 > cv1 ? cv0 : cv1;
    int inl = cvmax > 32 ? 32 : cvmax;
    int iters = (inl + 3) & ~3;

    // hoisted independent loads (in flight during gather)
    uint2 a = *(const uint2*)(z + (size_t)v * 256 + hl * 8);
    us8 xr = *(const us8*)(xh + (size_t)v * H_DIM + hl * 8);
    float4 bv0 = *(const float4*)(bias + hl * 8);
    float4 bv1 = *(const float4*)(bias + hl * 8 + 4);

    float sn = d * d;
    float acc[8];
    {
        f32x2 p0 = __builtin_amdgcn_cvt_pk_f32_fp8(a.x, false);
        f32x2 p1 = __builtin_amdgcn_cvt_pk_f32_fp8(a.x, true);
        f32x2 p2 = __builtin_amdgcn_cvt_pk_f32_fp8(a.y, false);
        f32x2 p3 = __builtin_amdgcn_cvt_pk_f32_fp8(a.y, true);
        acc[0] = sn * p0[0]; acc[1] = sn * p0[1];
        acc[2] = sn * p1[0]; acc[3] = sn * p1[1];
        acc[4] = sn * p2[0]; acc[5] = sn * p2[1];
        acc[6] = sn * p3[0]; acc[7] = sn * p3[1];
    }

    int base = h << 5;   // shfl source base for this half
    for (int k = 0; k < iters; k += 4) {
        int i0 = __shfl(nsrc, base + k);     float w0 = __shfl(nw, base + k);
        int i1 = __shfl(nsrc, base + k + 1); float w1 = __shfl(nw, base + k + 1);
        int i2 = __shfl(nsrc, base + k + 2); float w2 = __shfl(nw, base + k + 2);
        int i3 = __shfl(nsrc, base + k + 3); float w3 = __shfl(nw, base + k + 3);
        uint2 b0 = *(const uint2*)(z + (size_t)i0 * 256 + hl * 8);
        uint2 b1 = *(const uint2*)(z + (size_t)i1 * 256 + hl * 8);
        uint2 b2 = *(const uint2*)(z + (size_t)i2 * 256 + hl * 8);
        uint2 b3 = *(const uint2*)(z + (size_t)i3 * 256 + hl * 8);
        #pragma unroll
        for (int e4 = 0; e4 < 4; e4++) {
            uint2 bb = e4 == 0 ? b0 : (e4 == 1 ? b1 : (e4 == 2 ? b2 : b3));
            float ww = e4 == 0 ? w0 : (e4 == 1 ? w1 : (e4 == 2 ? w2 : w3));
            f32x2 p0 = __builtin_amdgcn_cvt_pk_f32_fp8(bb.x, false);
            f32x2 p1 = __builtin_amdgcn_cvt_pk_f32_fp8(bb.x, true);
            f32x2 p2 = __builtin_amdgcn_cvt_pk_f32_fp8(bb.y, false);
            f32x2 p3 = __builtin_amdgcn_cvt_pk_f32_fp8(bb.y, true);
            acc[0] += ww * p0[0]; acc[1] += ww * p0[1];
            acc[2] += ww * p1[0]; acc[3] += ww * p1[1];
            acc[4] += ww * p2[0]; acc[5] += ww * p2[1];
            acc[6] += ww * p3[0]; acc[7] += ww * p3[1];
        }
    }
    // overflow fallback (deg > 32 — statistically never for Poisson(8))
    for (int k = 32; k < cv; k++) {
        int2 ec = ecsr[s + k];
        float ww = __int_as_float(ec.y);
        uint2 bb = *(const uint2*)(z + (size_t)ec.x * 256 + hl * 8);
        f32x2 p0 = __builtin_amdgcn_cvt_pk_f32_fp8(bb.x, false);
        f32x2 p1 = __builtin_amdgcn_cvt_pk_f32_fp8(bb.x, true);
        f32x2 p2 = __builtin_amdgcn_cvt_pk_f32_fp8(bb.y, false);
        f32x2 p3 = __builtin_amdgcn_cvt_pk_f32_fp8(bb.y, true);
        acc[0] += ww * p0[0]; acc[1] += ww * p0[1];
        acc[2] += ww * p1[0]; acc[3] += ww * p1[1];
        acc[4] += ww * p2[0]; acc[5] += ww * p2[1];
        acc[6] += ww * p3[0]; acc[7] += ww * p3[1];
    }

    us8 o;
    o[0] = f2h(h2f(xr[0]) + lrelu(acc[0] + bv0.x));
    o[1] = f2h(h2f(xr[1]) + lrelu(acc[1] + bv0.y));
    o[2] = f2h(h2f(xr[2]) + lrelu(acc[2] + bv0.z));
    o[3] = f2h(h2f(xr[3]) + lrelu(acc[3] + bv0.w));
    o[4] = f2h(h2f(xr[4]) + lrelu(acc[4] + bv1.x));
    o[5] = f2h(h2f(xr[5]) + lrelu(acc[5] + bv1.y));
    o[6] = f2h(h2f(xr[6]) + lrelu(acc[6] + bv1.z));
    o[7] = f2h(h2f(xr[7]) + lrelu(acc[7] + bv1.w));
    *(us8*)(xh + (size_t)v * H_DIM + hl * 8) = o;
}

// ---------- pooling (3-stage tree) + head ----------

__global__ void k_pool1(const ushort_t* __restrict__ xh, float* __restrict__ partial) {
    __shared__ float s[4][256];
    int t = threadIdx.x;
    int w = t >> 6, lane = t & 63;
    size_t nodebase = (size_t)blockIdx.x * 64;
    float4 acc = make_float4(0.f, 0.f, 0.f, 0.f);
    for (int i = 0; i < 16; i++) {
        size_t node = nodebase + i * 4 + w;
        ushort4 v = *(const ushort4*)(xh + node * H_DIM + lane * 4);
        acc.x += h2f(v.x); acc.y += h2f(v.y); acc.z += h2f(v.z); acc.w += h2f(v.w);
    }
    *(float4*)&s[w][lane * 4] = acc;
    __syncthreads();
    float sum = s[0][t] + s[1][t] + s[2][t] + s[3][t];
    partial[(size_t)blockIdx.x * H_DIM + t] = sum;
}

__global__ void k_pool2(const float* __restrict__ partial, float* __restrict__ partial2,
                        int rowsPerChunk) {
    int blk = blockIdx.x, t = threadIdx.x;
    size_t rowbase = (size_t)blk * rowsPerChunk;
    float s = 0.f;
    for (int j = 0; j < rowsPerChunk; j++)
        s += partial[(rowbase + j) * H_DIM + t];
    partial2[(size_t)blk * H_DIM + t] = s;
}

__global__ void k_pool3(const float* __restrict__ partial2, float* __restrict__ pooled,
                        int chunksPerBatch, float inv) {
    int b = blockIdx.x, t = threadIdx.x;
    float s = 0.f;
    for (int j = 0; j < chunksPerBatch; j++)
        s += partial2[((size_t)b * chunksPerBatch + j) * H_DIM + t];
    pooled[b * H_DIM + t] = s * inv;
}

__global__ void k_head(const float* __restrict__ pooled, const float* __restrict__ Wh,
                       const float* __restrict__ bh, float* __restrict__ out) {
    int b = blockIdx.x, o = threadIdx.x;
    float acc = bh[o];
    for (int h = 0; h < H_DIM; h++) acc += pooled[b * H_DIM + h] * Wh[h * OUT_DIM + o];
    out[b * OUT_DIM + o] = acc;
}

// ---------- host ----------

extern "C" void kernel_launch(void* const* d_in, const int* in_sizes, int n_in,
                              void* d_out, int out_size, void* d_ws, size_t ws_size,
                              hipStream_t stream) {
    const float* sst  = (const float*)d_in[0];
    const int*   mask = (const int*)d_in[1];
    const int*   eidx = (const int*)d_in[2];
    const float* W1   = (const float*)d_in[3];
    const float* b1   = (const float*)d_in[4];
    const float* Ws   = (const float*)d_in[5];
    const float* bs   = (const float*)d_in[6];
    const float* Wh   = (const float*)d_in[7];
    const float* bh   = (const float*)d_in[8];

    const int B  = out_size / OUT_DIM;               // 2
    const int Nn = in_sizes[1];                      // 65536
    const int E  = in_sizes[2] / 2;                  // 1048576
    const int F  = in_sizes[0] / B;                  // 686364
    const int DEPTH = in_sizes[5] / (H_DIM * H_DIM); // 8
    const int NT = B * Nn;                           // 131072

    // workspace carve-up (256B aligned) — total ~125 MB
    size_t off = 0;
    char* base = (char*)d_ws;
    auto alloc = [&](size_t bytes) -> void* {
        void* p = base + off;
        off += (bytes + 255) & ~(size_t)255;
        return p;
    };
    ushort_t*      xh      = (ushort_t*)alloc((size_t)NT * H_DIM * 2);  // 67.1 MB fp16 residual
    unsigned char* zbuf    = (unsigned char*)alloc((size_t)NT * 256);   // 33.5 MB fp8
    float*    x0      = (float*)alloc((size_t)NT * 4);
    float*    y0      = (float*)alloc((size_t)NT * 4);
    int*      cnt     = (int*)alloc((size_t)NT * 4);
    int*      startp  = (int*)alloc((size_t)NT * 4);
    float*    dis     = (float*)alloc((size_t)NT * 4);
    int*      bsum    = (int*)alloc(4096);
    int*      bpre    = (int*)alloc(4096);
    int*      rank    = (int*)alloc((size_t)E * 4);                     // 4 MB
    int2*     ecsr    = (int2*)alloc((size_t)E * 8);                    // 8 MB
    ushort_t* Wt      = (ushort_t*)alloc((size_t)DEPTH * H_DIM * H_DIM * 2);  // 1 MB fp16
    float*    partial = (float*)alloc((size_t)(NT / 64) * H_DIM * 4);
    float*    partial2= (float*)alloc((size_t)64 * H_DIM * 4);
    float*    pooled  = (float*)alloc((size_t)B * H_DIM * 4);
    if (off > ws_size) return;   // workspace too small: fail visibly

    const int* esrc = eidx;
    const int* edst = eidx + E;

    dim3 blk(256);
    int gNT = (NT + 255) / 256;
    int gE  = (E + 255) / 256;
    int nb  = gNT;               // 512 scan blocks

    hipMemsetAsync(cnt, 0, (size_t)NT * 4, stream);

    k_gather_x0<<<gNT, blk, 0, stream>>>(sst, mask, x0, NT, Nn, F);
    k_count<<<gE, blk, 0, stream>>>(edst, cnt, rank, E);
    k_dis<<<gNT, blk, 0, stream>>>(cnt, dis, NT);
    k_scan_block<<<nb, blk, 0, stream>>>(cnt, bsum, NT);
    k_scan_top<<<1, 512, 0, stream>>>(bsum, bpre, nb);
    k_scan_scatter<<<nb, blk, 0, stream>>>(cnt, bpre, startp, NT);
    k_fill<<<gE, blk, 0, stream>>>(esrc, edst, rank, startp, dis, ecsr, E);
    k_prepW<<<(DEPTH * H_DIM * H_DIM + 255) / 256, blk, 0, stream>>>(Ws, Wt, DEPTH * H_DIM * H_DIM);

    // layer 1: scalar -> H (fp16 residual stream)
    k_agg0<<<gNT, blk, 0, stream>>>(x0, startp, cnt, ecsr, dis, y0, NT);
    k_expand<<<(NT * 64 + 255) / 256, blk, 0, stream>>>(x0, y0, W1, b1, xh, NT);

    // layers 2..9: z = xh@W (fp8 out), then aggregate+bias+leaky+residual into xh
    for (int l = 0; l < DEPTH; l++) {
        k_gemm<<<512, blk, 0, stream>>>(xh, Wt + (size_t)l * H_DIM * H_DIM, zbuf, NT);
        k_aggres<<<NT / 8, blk, 0, stream>>>(zbuf, startp, cnt, ecsr, dis,
                                             bs + (size_t)l * H_DIM, xh, NT);
    }

    // pool + head: 2048 -> 32 -> 2
    int pblocks = NT / 64;                 // 2048
    int chunksPerBatch = 16;
    int rowsPerChunk = (pblocks / B) / chunksPerBatch;   // 64
    k_pool1<<<pblocks, blk, 0, stream>>>(xh, partial);
    k_pool2<<<B * chunksPerBatch, blk, 0, stream>>>(partial, partial2, rowsPerChunk);
    k_pool3<<<B, blk, 0, stream>>>(partial2, pooled, chunksPerBatch, 1.0f / (float)Nn);
    k_head<<<B, blk, 0, stream>>>(pooled, Wh, bh, (float*)d_out);
}